// Round 11
// baseline (120.867 us; speedup 1.0000x reference)
//
#include <hip/hip_runtime.h>
#include <hip/hip_bf16.h>

// ---------------------------------------------------------------------------
// Round 11: LDS-free, UNJAMMED (16 samples/wave), 64-VGPR-budget kernel.
// r10 diagnosis: VGPR=80 lands in the 128-granule -> 4 waves/SIMD cap ->
// occupancy stuck at 29%, VALU 64% with ~36% stall dilution. This round:
// accumulators halved (no jam), phase-1 processes one GEMM1' tile at a time,
// phase-3 consumes GEMM2' weight frags in per-t 2-frag windows, so peak
// live regs ~60; __launch_bounds__(256,8) forces the 64-VGPR budget ->
// 8 waves/SIMD. Per-sample arithmetic identical to r9/r10 (absmax 0.0156).
//   GEMM1': D[c][m] = (W|b)^T s^T ; value 1-term, location 3-term (hi/lo)
//   exchange: packed bf16 pairs, 8 bpermute + 4 selects per stream
//   GEMM2': D[n][m]; each lane ends with (x,y,value) triples for 8
//           centroids of its own sample.  exp/tanh folded to exp2.
// ---------------------------------------------------------------------------

typedef __attribute__((ext_vector_type(8))) short bf16x8;
typedef __attribute__((ext_vector_type(4))) float f32x4;

// short-index offsets inside ws
#define OFF_V1  0        // 7 half-tiles x 256 (value GEMM1' A, hi)
#define OFF_L1H 1792     // 7 half-tiles x 256 (loc GEMM1' A, hi)
#define OFF_L1L 3584     // 7 half-tiles x 256 (loc GEMM1' A, lo)
#define OFF_W2  5376     // 2 n-tiles x 4 kt x 512 (values GEMM2' A, hi)
#define OFF_W3H 9472     // 4 c-tiles x 4 kt x 512 (centroid GEMM2' A, hi)
#define OFF_W3L 17664    // same, lo
#define TOT_SHORTS 25856 // 51712 bytes

__device__ __forceinline__ short f2bf(float x) {
    union { float f; unsigned u; } v; v.f = x;
    unsigned r = v.u + 0x7FFFu + ((v.u >> 16) & 1u);   // RNE
    return (short)(r >> 16);
}
__device__ __forceinline__ float bf2f(short h) {
    union { unsigned u; float f; } v; v.u = ((unsigned)(unsigned short)h) << 16;
    return v.f;
}
// pack two f32 -> one u32 of 2 bf16 (RNE; lowers to v_cvt_pk_bf16_f32)
__device__ __forceinline__ unsigned cvt2(float a, float b) {
    union { __hip_bfloat162 h; unsigned u; } U;
    U.h = __float22bfloat162_rn(float2{a, b});
    return U.u;
}
__device__ __forceinline__ float lo16f(unsigned u) {
    union { unsigned u; float f; } V; V.u = u << 16; return V.f;
}
__device__ __forceinline__ float hi16f(unsigned u) {
    union { unsigned u; float f; } V; V.u = u & 0xFFFF0000u; return V.f;
}
// tanh(x) = 1 - 2/(exp2(x*2*log2e)+1)
__device__ __forceinline__ float tanh_fast(float x) {
    float e = exp2f(2.8853900817779268f * x);
    return 1.f - 2.f / (e + 1.f);
}

// ---------------- prologue: build fragment-layout weights in ws ------------
__global__ __launch_bounds__(256) void prep_kernel(
    const float* __restrict__ W1, const float* __restrict__ b1,
    const float* __restrict__ W2, const float* __restrict__ b2,
    const float* __restrict__ L1, const float* __restrict__ bl1,
    const float* __restrict__ WL2, const float* __restrict__ bL2,
    short* __restrict__ ws)
{
    int idx = blockIdx.x * 256 + threadIdx.x;
    if (idx >= TOT_SHORTS) return;
    float val = 0.f;
    bool want_lo = false;

    if (idx < OFF_W2) {
        // GEMM1' A half-tiles: [region r][tile t][lane 0..31][j 0..7]
        int r = idx / 1792;              // 0 = W1(hi), 1 = L1(hi), 2 = L1(lo)
        int rem = idx - r * 1792;
        int t = rem >> 8, e = rem & 255;
        int ln = e >> 3, j = e & 7;      // ln 0..31
        int c = t * 16 + (ln & 15);      // hidden unit (row of A)
        int k = (ln >> 4) * 8 + j;       // 0..15 (real k: 0..10)
        const float* W  = (r == 0) ? W1 : L1;
        const float* bb = (r == 0) ? b1 : bl1;
        if (c < 100)       val = (k < 10) ? W[k * 100 + c] : ((k == 10) ? bb[c] : 0.f);
        else if (c == 100) val = (k == 10) ? 1.f : 0.f;    // generates h[100]=1 bias row
        want_lo = (r == 2);
    } else if (idx < OFF_W3H) {
        // GEMM2a' A: [T 0..1][kt 0..3][lane 0..63][j]
        int i2 = idx - OFF_W2;
        int T = i2 >> 11, kt = (i2 >> 9) & 3, e = i2 & 511;
        int ln = e >> 3, j = e & 7;
        int rho = ln & 15;
        int k = kt * 32 + (ln >> 4) * 8 + j;
        int n = 16 * T + 2 * (rho >> 2) + ((rho & 3) >> 1) * 8 + (rho & 1);
        if (n < 30) val = (k < 100) ? W2[k * 30 + n] : ((k == 100) ? b2[n] : 0.f);
    } else {
        // GEMM2b' A: [half h][t 0..3][kt][lane][j]
        int i3 = idx - OFF_W3H;
        want_lo = (i3 >= 8192); i3 &= 8191;
        int t = i3 >> 11, kt = (i3 >> 9) & 3, e = i3 & 511;
        int ln = e >> 3, j = e & 7;
        int rho = ln & 15;
        int k = kt * 32 + (ln >> 4) * 8 + j;
        int n = 8 * t + 2 * (rho >> 2) + ((rho & 3) >> 1);
        int d = rho & 1;
        if (n < 30) val = (k < 100) ? WL2[(n * 100 + k) * 2 + d]
                                    : ((k == 100) ? bL2[n * 2 + d] : 0.f);
    }
    short hi = f2bf(val);
    ws[idx] = want_lo ? f2bf(val - bf2f(hi)) : hi;
}

// ---------------- main fused kernel (no LDS, 16 samples/wave) --------------
__global__ __launch_bounds__(256, 8) void fused_kernel(
    const float* __restrict__ s, const float* __restrict__ a,
    const short* __restrict__ ws, float* __restrict__ out)
{
    const int tid  = threadIdx.x;
    const int lane = tid & 63;
    const int wave = tid >> 6;
    const int m    = lane & 15;
    const int G    = lane >> 4;
    const int wgbase = blockIdx.x * 64;    // 4 waves x 16 samples
    const int m0   = wave * 16;

    const int srcA = m | ((2 * (G & 1)) << 4);
    const int srcB = srcA | 16;
    const bool hiTile = (G >> 1) != 0;     // this lane's k-range lives in tile t0+1

    const bf16x8 bz = {0, 0, 0, 0, 0, 0, 0, 0};
    const f32x4 fz = {0.f, 0.f, 0.f, 0.f};

    union Frag { bf16x8 v; unsigned u[4]; };

    // ---- s^T B-frag (hi + lo); lanes>=32 zero; k=10 is bias-1 row ----------
    bf16x8 sh, sl;
    {
        Frag H, L; H.v = bz; L.v = bz;
        const float2* p = (const float2*)(s + (size_t)(wgbase + m0 + m) * 10);
        if (G == 0) {
            float2 q0 = p[0], q1 = p[1], q2 = p[2], q3 = p[3];
            float qs[8] = {q0.x, q0.y, q1.x, q1.y, q2.x, q2.y, q3.x, q3.y};
            #pragma unroll
            for (int i = 0; i < 4; ++i) {
                unsigned uh = cvt2(qs[2 * i], qs[2 * i + 1]);
                H.u[i] = uh;
                L.u[i] = cvt2(qs[2 * i] - lo16f(uh), qs[2 * i + 1] - hi16f(uh));
            }
        } else if (G == 1) {
            float2 q4 = p[4];
            unsigned uh = cvt2(q4.x, q4.y);
            H.u[0] = uh;
            L.u[0] = cvt2(q4.x - lo16f(uh), q4.y - hi16f(uh));
            H.u[1] = 0x00003F80u;  // element 2: k = 10 -> 1.0 (bias row)
        }
        sh = H.v; sl = L.v;
    }

    // GEMM1' one tile: load frags + MFMA + relu + pack (frags die on return)
    auto g1t = [&](int t, unsigned& qv0, unsigned& qv1,
                   unsigned& qh0, unsigned& qh1,
                   unsigned& ql0, unsigned& ql1) {
        bf16x8 aV = bz, aH = bz, aL = bz;
        if (lane < 32) {
            aV = *(const bf16x8*)(ws + OFF_V1  + t * 256 + lane * 8);
            aH = *(const bf16x8*)(ws + OFF_L1H + t * 256 + lane * 8);
            aL = *(const bf16x8*)(ws + OFF_L1L + t * 256 + lane * 8);
        }
        f32x4 dv = __builtin_amdgcn_mfma_f32_16x16x32_bf16(aV, sh, fz, 0, 0, 0);
        f32x4 dh = __builtin_amdgcn_mfma_f32_16x16x32_bf16(aH, sh, fz, 0, 0, 0);
        dh = __builtin_amdgcn_mfma_f32_16x16x32_bf16(aH, sl, dh, 0, 0, 0);
        dh = __builtin_amdgcn_mfma_f32_16x16x32_bf16(aL, sh, dh, 0, 0, 0);

        qv0 = cvt2(fmaxf(dv[0], 0.f), fmaxf(dv[1], 0.f));
        qv1 = cvt2(fmaxf(dv[2], 0.f), fmaxf(dv[3], 0.f));

        float h0 = fmaxf(dh[0], 0.f), h1f = fmaxf(dh[1], 0.f);
        float h2 = fmaxf(dh[2], 0.f), h3 = fmaxf(dh[3], 0.f);
        qh0 = cvt2(h0, h1f);
        qh1 = cvt2(h2, h3);
        ql0 = cvt2(h0 - lo16f(qh0), h1f - hi16f(qh0));
        ql1 = cvt2(h2 - lo16f(qh1), h3 - hi16f(qh1));
    };

    // exchange: build GEMM2' B-frag for one kt from two tiles' pack words
    auto xch4 = [&](unsigned a0, unsigned a1, unsigned b0, unsigned b1,
                    bool hasT1) -> bf16x8 {
        unsigned e0 = (unsigned)__shfl((int)a0, srcA);
        unsigned e1 = (unsigned)__shfl((int)a1, srcA);
        unsigned e2 = (unsigned)__shfl((int)a0, srcB);
        unsigned e3 = (unsigned)__shfl((int)a1, srcB);
        unsigned f0 = 0, f1 = 0, f2 = 0, f3 = 0;
        if (hasT1) {
            f0 = (unsigned)__shfl((int)b0, srcA);
            f1 = (unsigned)__shfl((int)b1, srcA);
            f2 = (unsigned)__shfl((int)b0, srcB);
            f3 = (unsigned)__shfl((int)b1, srcB);
        }
        Frag U;
        U.u[0] = hiTile ? f0 : e0;
        U.u[1] = hiTile ? f1 : e1;
        U.u[2] = hiTile ? f2 : e2;
        U.u[3] = hiTile ? f3 : e3;
        return U.v;
    };

    f32x4 DV[2] = {fz, fz};
    f32x4 DC[4] = {fz, fz, fz, fz};

    #pragma unroll 1
    for (int kt = 0; kt < 4; ++kt) {
        const bool h1 = (kt < 3);
        const int t0 = 2 * kt;

        // ---- phase 1: GEMM1' tiles t0 (and t0+1), one at a time ------------
        unsigned Av0, Av1, Ah0, Ah1, Al0, Al1;
        unsigned Bv0 = 0, Bv1 = 0, Bh0 = 0, Bh1 = 0, Bl0 = 0, Bl1 = 0;
        g1t(t0, Av0, Av1, Ah0, Ah1, Al0, Al1);
        if (h1) g1t(t0 + 1, Bv0, Bv1, Bh0, Bh1, Bl0, Bl1);

        // ---- phase 2: exchange (bpermute crossbar) -------------------------
        bf16x8 bv = xch4(Av0, Av1, Bv0, Bv1, h1);
        bf16x8 bh = xch4(Ah0, Ah1, Bh0, Bh1, h1);
        bf16x8 bl = xch4(Al0, Al1, Bl0, Bl1, h1);

        // ---- phase 3: GEMM2' in small register windows ---------------------
        {
            bf16x8 w0 = *(const bf16x8*)(ws + OFF_W2 + (0 * 4 + kt) * 512 + lane * 8);
            bf16x8 w1 = *(const bf16x8*)(ws + OFF_W2 + (1 * 4 + kt) * 512 + lane * 8);
            DV[0] = __builtin_amdgcn_mfma_f32_16x16x32_bf16(w0, bv, DV[0], 0, 0, 0);
            DV[1] = __builtin_amdgcn_mfma_f32_16x16x32_bf16(w1, bv, DV[1], 0, 0, 0);
        }
        #pragma unroll
        for (int t = 0; t < 4; ++t) {
            bf16x8 wh = *(const bf16x8*)(ws + OFF_W3H + (t * 4 + kt) * 512 + lane * 8);
            bf16x8 wl = *(const bf16x8*)(ws + OFF_W3L + (t * 4 + kt) * 512 + lane * 8);
            DC[t] = __builtin_amdgcn_mfma_f32_16x16x32_bf16(wh, bh, DC[t], 0, 0, 0);
            DC[t] = __builtin_amdgcn_mfma_f32_16x16x32_bf16(wh, bl, DC[t], 0, 0, 0);
            DC[t] = __builtin_amdgcn_mfma_f32_16x16x32_bf16(wl, bh, DC[t], 0, 0, 0);
        }
    }

    // ---- epilogue: per-lane 8 centroids of its own sample -------------------
    {
        float2 av = ((const float2*)a)[wgbase + m0 + m];
        float num = 0.f, den = 0.f;
        #pragma unroll
        for (int t = 0; t < 4; ++t) {
            #pragma unroll
            for (int p = 0; p < 2; ++p) {
                float x = 5.f * tanh_fast(DC[t][2 * p]);
                float y = 5.f * tanh_fast(DC[t][2 * p + 1]);
                float ex = x - av.x, ey = y - av.y;
                float dist = sqrtf(fmaf(ex, ex, ey * ey));
                float wt = exp2f(-4.328085122666891f * dist);   // exp(-3 d)
                if (t == 3 && G == 3) wt = 0.f;      // n = 30,31 pad
                float v = (t < 2) ? DV[0][2 * t + p] : DV[1][2 * (t - 2) + p];
                num = fmaf(wt, v, num);
                den += wt;
            }
        }
        num += __shfl_xor(num, 16); den += __shfl_xor(den, 16);
        num += __shfl_xor(num, 32); den += __shfl_xor(den, 32);
        if (lane < 16) out[wgbase + m0 + m] = num / den;
    }
}

extern "C" void kernel_launch(void* const* d_in, const int* in_sizes, int n_in,
                              void* d_out, int out_size, void* d_ws, size_t ws_size,
                              hipStream_t stream) {
    const float* s   = (const float*)d_in[0];
    const float* a   = (const float*)d_in[1];
    const float* W1  = (const float*)d_in[2];
    const float* b1  = (const float*)d_in[3];
    const float* W2  = (const float*)d_in[4];
    const float* b2  = (const float*)d_in[5];
    const float* L1  = (const float*)d_in[6];
    const float* bl1 = (const float*)d_in[7];
    const float* WL2 = (const float*)d_in[8];
    const float* bL2 = (const float*)d_in[9];
    float* out = (float*)d_out;
    short* ws  = (short*)d_ws;

    prep_kernel<<<(TOT_SHORTS + 255) / 256, 256, 0, stream>>>(
        W1, b1, W2, b2, L1, bl1, WL2, bL2, ws);

    int Btot = out_size;                 // 524288
    int grid = Btot / 64;                // 8192 WGs, 16 samples/wave
    fused_kernel<<<grid, 256, 0, stream>>>(s, a, ws, out);
}

// Round 13
// 67.623 us; speedup vs baseline: 1.7873x; 1.7873x over previous
//
#include <hip/hip_runtime.h>
#include <hip/hip_fp16.h>

// ---------------------------------------------------------------------------
// Round 13 (= r12 with compile fix): f16 single-term everywhere.
// f16 mantissa (10b) vs bf16 (7b): r2 measured bf16-1-term absmax 0.17 ->
// f16-1-term ~0.02-0.04 < 0.0856 threshold. Deletes all lo-streams:
//   MFMA/16-samples: 84 -> 38, bpermutes: 144 -> 64, regs ~80 -> ~60.
// LDS-free, unjammed (16 samples/wave), kt-outer, phase-windowed loads.
// Weights converted RNE once in prep; in-loop h packed via v_cvt_pkrtz (RTZ);
// s-frag packed RNE (once per wave).
//   GEMM1': D[c][m] = (W|b)^T s^T  (value + location, 1-term f16)
//   exchange: packed f16 pairs, 8 bpermute + 4 selects per stream (2 streams)
//   GEMM2': D[n][m]; each lane ends with (x,y,value) triples for 8
//           centroids of its own sample. exp/tanh folded to exp2.
// ---------------------------------------------------------------------------

typedef _Float16 f16x8 __attribute__((ext_vector_type(8)));
typedef __fp16 fp16x2 __attribute__((ext_vector_type(2)));   // cvt_pkrtz return type
typedef __attribute__((ext_vector_type(4))) float f32x4;

// half-index offsets inside ws
#define OFF_V1 0        // 7 half-tiles x 256 (value GEMM1' A)
#define OFF_L1 1792     // 7 half-tiles x 256 (loc GEMM1' A)
#define OFF_W2 3584     // 2 n-tiles x 4 kt x 512 (values GEMM2' A)
#define OFF_W3 7680     // 4 c-tiles x 4 kt x 512 (centroid GEMM2' A)
#define TOT_HALVES 15872 // 31744 bytes

// pack two f32 -> one u32 of 2 f16, RTZ (v_cvt_pkrtz_f16_f32, 1 instr)
__device__ __forceinline__ unsigned pkrtz(float a, float b) {
    union { fp16x2 v; unsigned u; } U;
    U.v = __builtin_amdgcn_cvt_pkrtz(a, b);
    return U.u;
}
// RNE pack (2x v_cvt_f16_f32 + pack) — used off the hot path
__device__ __forceinline__ unsigned pk_rne(float a, float b) {
    union { __half h[2]; unsigned u; } U;
    U.h[0] = __float2half(a);
    U.h[1] = __float2half(b);
    return U.u;
}
// tanh(x) = 1 - 2/(exp2(x*2*log2e)+1)
__device__ __forceinline__ float tanh_fast(float x) {
    float e = exp2f(2.8853900817779268f * x);
    return 1.f - 2.f / (e + 1.f);
}

// ---------------- prologue: build fragment-layout weights in ws (f16) ------
__global__ __launch_bounds__(256) void prep_kernel(
    const float* __restrict__ W1, const float* __restrict__ b1,
    const float* __restrict__ W2, const float* __restrict__ b2,
    const float* __restrict__ L1, const float* __restrict__ bl1,
    const float* __restrict__ WL2, const float* __restrict__ bL2,
    unsigned short* __restrict__ ws)
{
    int idx = blockIdx.x * 256 + threadIdx.x;
    if (idx >= TOT_HALVES) return;
    float val = 0.f;

    if (idx < OFF_W2) {
        // GEMM1' A half-tiles: [region r][tile t][lane 0..31][j 0..7]
        int r = idx / 1792;              // 0 = W1, 1 = L1
        int rem = idx - r * 1792;
        int t = rem >> 8, e = rem & 255;
        int ln = e >> 3, j = e & 7;      // ln 0..31
        int c = t * 16 + (ln & 15);      // hidden unit (row of A)
        int k = (ln >> 4) * 8 + j;       // 0..15 (real k: 0..10)
        const float* W  = (r == 0) ? W1 : L1;
        const float* bb = (r == 0) ? b1 : bl1;
        if (c < 100)       val = (k < 10) ? W[k * 100 + c] : ((k == 10) ? bb[c] : 0.f);
        else if (c == 100) val = (k == 10) ? 1.f : 0.f;    // h[100]=1 bias row
    } else if (idx < OFF_W3) {
        // GEMM2a' A: [T 0..1][kt 0..3][lane 0..63][j]
        int i2 = idx - OFF_W2;
        int T = i2 >> 11, kt = (i2 >> 9) & 3, e = i2 & 511;
        int ln = e >> 3, j = e & 7;
        int rho = ln & 15;
        int k = kt * 32 + (ln >> 4) * 8 + j;
        int n = 16 * T + 2 * (rho >> 2) + ((rho & 3) >> 1) * 8 + (rho & 1);
        if (n < 30) val = (k < 100) ? W2[k * 30 + n] : ((k == 100) ? b2[n] : 0.f);
    } else {
        // GEMM2b' A: [t 0..3][kt][lane][j]
        int i3 = idx - OFF_W3;
        int t = i3 >> 11, kt = (i3 >> 9) & 3, e = i3 & 511;
        int ln = e >> 3, j = e & 7;
        int rho = ln & 15;
        int k = kt * 32 + (ln >> 4) * 8 + j;
        int n = 8 * t + 2 * (rho >> 2) + ((rho & 3) >> 1);
        int d = rho & 1;
        if (n < 30) val = (k < 100) ? WL2[(n * 100 + k) * 2 + d]
                                    : ((k == 100) ? bL2[n * 2 + d] : 0.f);
    }
    union { __half h; unsigned short u; } cv;
    cv.h = __float2half(val);            // RNE
    ws[idx] = cv.u;
}

// ---------------- main fused kernel (no LDS, 16 samples/wave, f16) ---------
__global__ __launch_bounds__(256, 4) void fused_kernel(
    const float* __restrict__ s, const float* __restrict__ a,
    const unsigned short* __restrict__ ws, float* __restrict__ out)
{
    const int tid  = threadIdx.x;
    const int lane = tid & 63;
    const int wave = tid >> 6;
    const int m    = lane & 15;
    const int G    = lane >> 4;
    const int wgbase = blockIdx.x * 64;    // 4 waves x 16 samples
    const int m0   = wave * 16;

    const int srcA = m | ((2 * (G & 1)) << 4);
    const int srcB = srcA | 16;
    const bool hiTile = (G >> 1) != 0;     // this lane's k-range lives in tile t0+1

    const f16x8 hz = {0, 0, 0, 0, 0, 0, 0, 0};
    const f32x4 fz = {0.f, 0.f, 0.f, 0.f};

    union Frag { f16x8 v; unsigned u[4]; };

    // ---- s^T B-frag; lanes>=32 zero; k=10 is bias-1 row (RNE pack) ---------
    f16x8 sh;
    {
        Frag H; H.v = hz;
        const float2* p = (const float2*)(s + (size_t)(wgbase + m0 + m) * 10);
        if (G == 0) {
            float2 q0 = p[0], q1 = p[1], q2 = p[2], q3 = p[3];
            H.u[0] = pk_rne(q0.x, q0.y);
            H.u[1] = pk_rne(q1.x, q1.y);
            H.u[2] = pk_rne(q2.x, q2.y);
            H.u[3] = pk_rne(q3.x, q3.y);
        } else if (G == 1) {
            float2 q4 = p[4];
            H.u[0] = pk_rne(q4.x, q4.y);
            H.u[1] = 0x00003C00u;  // element 2: k = 10 -> f16 1.0 (bias row)
        }
        sh = H.v;
    }

    // GEMM1' one tile: load frags + 2 MFMA + relu + pack (frags die on return)
    auto g1t = [&](int t, unsigned& qv0, unsigned& qv1,
                   unsigned& qh0, unsigned& qh1) {
        f16x8 aV = hz, aH = hz;
        if (lane < 32) {
            aV = *(const f16x8*)(ws + OFF_V1 + t * 256 + lane * 8);
            aH = *(const f16x8*)(ws + OFF_L1 + t * 256 + lane * 8);
        }
        f32x4 dv = __builtin_amdgcn_mfma_f32_16x16x32_f16(aV, sh, fz, 0, 0, 0);
        f32x4 dh = __builtin_amdgcn_mfma_f32_16x16x32_f16(aH, sh, fz, 0, 0, 0);

        qv0 = pkrtz(fmaxf(dv[0], 0.f), fmaxf(dv[1], 0.f));
        qv1 = pkrtz(fmaxf(dv[2], 0.f), fmaxf(dv[3], 0.f));
        qh0 = pkrtz(fmaxf(dh[0], 0.f), fmaxf(dh[1], 0.f));
        qh1 = pkrtz(fmaxf(dh[2], 0.f), fmaxf(dh[3], 0.f));
    };

    // exchange: build GEMM2' B-frag for one kt from two tiles' pack words
    auto xch4 = [&](unsigned a0, unsigned a1, unsigned b0, unsigned b1,
                    bool hasT1) -> f16x8 {
        unsigned e0 = (unsigned)__shfl((int)a0, srcA);
        unsigned e1 = (unsigned)__shfl((int)a1, srcA);
        unsigned e2 = (unsigned)__shfl((int)a0, srcB);
        unsigned e3 = (unsigned)__shfl((int)a1, srcB);
        unsigned f0 = 0, f1 = 0, f2 = 0, f3 = 0;
        if (hasT1) {
            f0 = (unsigned)__shfl((int)b0, srcA);
            f1 = (unsigned)__shfl((int)b1, srcA);
            f2 = (unsigned)__shfl((int)b0, srcB);
            f3 = (unsigned)__shfl((int)b1, srcB);
        }
        Frag U;
        U.u[0] = hiTile ? f0 : e0;
        U.u[1] = hiTile ? f1 : e1;
        U.u[2] = hiTile ? f2 : e2;
        U.u[3] = hiTile ? f3 : e3;
        return U.v;
    };

    f32x4 DV[2] = {fz, fz};
    f32x4 DC[4] = {fz, fz, fz, fz};

    #pragma unroll 1
    for (int kt = 0; kt < 4; ++kt) {
        const bool h1 = (kt < 3);
        const int t0 = 2 * kt;

        // ---- phase 1: GEMM1' tiles t0 (and t0+1), one at a time ------------
        unsigned Av0, Av1, Ah0, Ah1;
        unsigned Bv0 = 0, Bv1 = 0, Bh0 = 0, Bh1 = 0;
        g1t(t0, Av0, Av1, Ah0, Ah1);
        if (h1) g1t(t0 + 1, Bv0, Bv1, Bh0, Bh1);

        // ---- phase 2: exchange (2 streams) ---------------------------------
        f16x8 bv = xch4(Av0, Av1, Bv0, Bv1, h1);
        f16x8 bh = xch4(Ah0, Ah1, Bh0, Bh1, h1);

        // ---- phase 3: GEMM2' in small register windows ---------------------
        {
            f16x8 w0 = *(const f16x8*)(ws + OFF_W2 + (0 * 4 + kt) * 512 + lane * 8);
            f16x8 w1 = *(const f16x8*)(ws + OFF_W2 + (1 * 4 + kt) * 512 + lane * 8);
            DV[0] = __builtin_amdgcn_mfma_f32_16x16x32_f16(w0, bv, DV[0], 0, 0, 0);
            DV[1] = __builtin_amdgcn_mfma_f32_16x16x32_f16(w1, bv, DV[1], 0, 0, 0);
        }
        #pragma unroll
        for (int t = 0; t < 4; ++t) {
            f16x8 wh = *(const f16x8*)(ws + OFF_W3 + (t * 4 + kt) * 512 + lane * 8);
            DC[t] = __builtin_amdgcn_mfma_f32_16x16x32_f16(wh, bh, DC[t], 0, 0, 0);
        }
    }

    // ---- epilogue: per-lane 8 centroids of its own sample -------------------
    {
        float2 av = ((const float2*)a)[wgbase + m0 + m];
        float num = 0.f, den = 0.f;
        #pragma unroll
        for (int t = 0; t < 4; ++t) {
            #pragma unroll
            for (int p = 0; p < 2; ++p) {
                float x = 5.f * tanh_fast(DC[t][2 * p]);
                float y = 5.f * tanh_fast(DC[t][2 * p + 1]);
                float ex = x - av.x, ey = y - av.y;
                float dist = sqrtf(fmaf(ex, ex, ey * ey));
                float wt = exp2f(-4.328085122666891f * dist);   // exp(-3 d)
                if (t == 3 && G == 3) wt = 0.f;      // n = 30,31 pad
                float v = (t < 2) ? DV[0][2 * t + p] : DV[1][2 * (t - 2) + p];
                num = fmaf(wt, v, num);
                den += wt;
            }
        }
        num += __shfl_xor(num, 16); den += __shfl_xor(den, 16);
        num += __shfl_xor(num, 32); den += __shfl_xor(den, 32);
        if (lane < 16) out[wgbase + m0 + m] = num / den;
    }
}

extern "C" void kernel_launch(void* const* d_in, const int* in_sizes, int n_in,
                              void* d_out, int out_size, void* d_ws, size_t ws_size,
                              hipStream_t stream) {
    const float* s   = (const float*)d_in[0];
    const float* a   = (const float*)d_in[1];
    const float* W1  = (const float*)d_in[2];
    const float* b1  = (const float*)d_in[3];
    const float* W2  = (const float*)d_in[4];
    const float* b2  = (const float*)d_in[5];
    const float* L1  = (const float*)d_in[6];
    const float* bl1 = (const float*)d_in[7];
    const float* WL2 = (const float*)d_in[8];
    const float* bL2 = (const float*)d_in[9];
    float* out = (float*)d_out;
    unsigned short* ws = (unsigned short*)d_ws;

    prep_kernel<<<(TOT_HALVES + 255) / 256, 256, 0, stream>>>(
        W1, b1, W2, b2, L1, bl1, WL2, bL2, ws);

    int Btot = out_size;                 // 524288
    int grid = Btot / 64;                // 8192 WGs, 16 samples/wave
    fused_kernel<<<grid, 256, 0, stream>>>(s, a, ws, out);
}

// Round 14
// 57.444 us; speedup vs baseline: 2.1041x; 1.1772x over previous
//
#include <hip/hip_runtime.h>
#include <hip/hip_fp16.h>

// ---------------------------------------------------------------------------
// Round 14: r13 (f16 single-term, LDS-free, 16 samples/wave) + VALU cuts:
//   1. kt loop fully unrolled -> ws addresses become immediates
//   2. v_rcp_f32 via __builtin_amdgcn_rcpf for tanh + final num/den
//      (plain '/' lowers to ~9-op correctly-rounded sequence; approx err
//       ~1e-7 vs 0.0856 threshold)
//   3. v_sqrt_f32 via __builtin_amdgcn_sqrtf for dist
//   GEMM1': D[c][m] = (W|b)^T s^T  (value + location, 1-term f16)
//   exchange: packed f16 pairs, 8 bpermute + 4 selects per stream (2 streams)
//   GEMM2': D[n][m]; each lane ends with (x,y,value) triples for 8
//           centroids of its own sample. exp/tanh folded to exp2.
// ---------------------------------------------------------------------------

typedef _Float16 f16x8 __attribute__((ext_vector_type(8)));
typedef __fp16 fp16x2 __attribute__((ext_vector_type(2)));   // cvt_pkrtz return type
typedef __attribute__((ext_vector_type(4))) float f32x4;

// half-index offsets inside ws
#define OFF_V1 0        // 7 half-tiles x 256 (value GEMM1' A)
#define OFF_L1 1792     // 7 half-tiles x 256 (loc GEMM1' A)
#define OFF_W2 3584     // 2 n-tiles x 4 kt x 512 (values GEMM2' A)
#define OFF_W3 7680     // 4 c-tiles x 4 kt x 512 (centroid GEMM2' A)
#define TOT_HALVES 15872 // 31744 bytes

// pack two f32 -> one u32 of 2 f16, RTZ (v_cvt_pkrtz_f16_f32, 1 instr)
__device__ __forceinline__ unsigned pkrtz(float a, float b) {
    union { fp16x2 v; unsigned u; } U;
    U.v = __builtin_amdgcn_cvt_pkrtz(a, b);
    return U.u;
}
// RNE pack (2x v_cvt_f16_f32 + pack) — used off the hot path
__device__ __forceinline__ unsigned pk_rne(float a, float b) {
    union { __half h[2]; unsigned u; } U;
    U.h[0] = __float2half(a);
    U.h[1] = __float2half(b);
    return U.u;
}
// tanh(x) = 1 - 2/(exp2(x*2*log2e)+1), rcp via v_rcp_f32 (1 instr)
__device__ __forceinline__ float tanh_fast(float x) {
    float e = exp2f(2.8853900817779268f * x);
    return 1.f - 2.f * __builtin_amdgcn_rcpf(e + 1.f);
}

// ---------------- prologue: build fragment-layout weights in ws (f16) ------
__global__ __launch_bounds__(256) void prep_kernel(
    const float* __restrict__ W1, const float* __restrict__ b1,
    const float* __restrict__ W2, const float* __restrict__ b2,
    const float* __restrict__ L1, const float* __restrict__ bl1,
    const float* __restrict__ WL2, const float* __restrict__ bL2,
    unsigned short* __restrict__ ws)
{
    int idx = blockIdx.x * 256 + threadIdx.x;
    if (idx >= TOT_HALVES) return;
    float val = 0.f;

    if (idx < OFF_W2) {
        // GEMM1' A half-tiles: [region r][tile t][lane 0..31][j 0..7]
        int r = idx / 1792;              // 0 = W1, 1 = L1
        int rem = idx - r * 1792;
        int t = rem >> 8, e = rem & 255;
        int ln = e >> 3, j = e & 7;      // ln 0..31
        int c = t * 16 + (ln & 15);      // hidden unit (row of A)
        int k = (ln >> 4) * 8 + j;       // 0..15 (real k: 0..10)
        const float* W  = (r == 0) ? W1 : L1;
        const float* bb = (r == 0) ? b1 : bl1;
        if (c < 100)       val = (k < 10) ? W[k * 100 + c] : ((k == 10) ? bb[c] : 0.f);
        else if (c == 100) val = (k == 10) ? 1.f : 0.f;    // h[100]=1 bias row
    } else if (idx < OFF_W3) {
        // GEMM2a' A: [T 0..1][kt 0..3][lane 0..63][j]
        int i2 = idx - OFF_W2;
        int T = i2 >> 11, kt = (i2 >> 9) & 3, e = i2 & 511;
        int ln = e >> 3, j = e & 7;
        int rho = ln & 15;
        int k = kt * 32 + (ln >> 4) * 8 + j;
        int n = 16 * T + 2 * (rho >> 2) + ((rho & 3) >> 1) * 8 + (rho & 1);
        if (n < 30) val = (k < 100) ? W2[k * 30 + n] : ((k == 100) ? b2[n] : 0.f);
    } else {
        // GEMM2b' A: [t 0..3][kt][lane][j]
        int i3 = idx - OFF_W3;
        int t = i3 >> 11, kt = (i3 >> 9) & 3, e = i3 & 511;
        int ln = e >> 3, j = e & 7;
        int rho = ln & 15;
        int k = kt * 32 + (ln >> 4) * 8 + j;
        int n = 8 * t + 2 * (rho >> 2) + ((rho & 3) >> 1);
        int d = rho & 1;
        if (n < 30) val = (k < 100) ? WL2[(n * 100 + k) * 2 + d]
                                    : ((k == 100) ? bL2[n * 2 + d] : 0.f);
    }
    union { __half h; unsigned short u; } cv;
    cv.h = __float2half(val);            // RNE
    ws[idx] = cv.u;
}

// ---------------- main fused kernel (no LDS, 16 samples/wave, f16) ---------
__global__ __launch_bounds__(256, 4) void fused_kernel(
    const float* __restrict__ s, const float* __restrict__ a,
    const unsigned short* __restrict__ ws, float* __restrict__ out)
{
    const int tid  = threadIdx.x;
    const int lane = tid & 63;
    const int wave = tid >> 6;
    const int m    = lane & 15;
    const int G    = lane >> 4;
    const int wgbase = blockIdx.x * 64;    // 4 waves x 16 samples
    const int m0   = wave * 16;

    const int srcA = m | ((2 * (G & 1)) << 4);
    const int srcB = srcA | 16;
    const bool hiTile = (G >> 1) != 0;     // this lane's k-range lives in tile t0+1

    const f16x8 hz = {0, 0, 0, 0, 0, 0, 0, 0};
    const f32x4 fz = {0.f, 0.f, 0.f, 0.f};

    union Frag { f16x8 v; unsigned u[4]; };

    // ---- s^T B-frag; lanes>=32 zero; k=10 is bias-1 row (RNE pack) ---------
    f16x8 sh;
    {
        Frag H; H.v = hz;
        const float2* p = (const float2*)(s + (size_t)(wgbase + m0 + m) * 10);
        if (G == 0) {
            float2 q0 = p[0], q1 = p[1], q2 = p[2], q3 = p[3];
            H.u[0] = pk_rne(q0.x, q0.y);
            H.u[1] = pk_rne(q1.x, q1.y);
            H.u[2] = pk_rne(q2.x, q2.y);
            H.u[3] = pk_rne(q3.x, q3.y);
        } else if (G == 1) {
            float2 q4 = p[4];
            H.u[0] = pk_rne(q4.x, q4.y);
            H.u[1] = 0x00003C00u;  // element 2: k = 10 -> f16 1.0 (bias row)
        }
        sh = H.v;
    }

    // GEMM1' one tile: load frags + 2 MFMA + relu + pack (frags die on return)
    auto g1t = [&](int t, unsigned& qv0, unsigned& qv1,
                   unsigned& qh0, unsigned& qh1) {
        f16x8 aV = hz, aH = hz;
        if (lane < 32) {
            aV = *(const f16x8*)(ws + OFF_V1 + t * 256 + lane * 8);
            aH = *(const f16x8*)(ws + OFF_L1 + t * 256 + lane * 8);
        }
        f32x4 dv = __builtin_amdgcn_mfma_f32_16x16x32_f16(aV, sh, fz, 0, 0, 0);
        f32x4 dh = __builtin_amdgcn_mfma_f32_16x16x32_f16(aH, sh, fz, 0, 0, 0);

        qv0 = pkrtz(fmaxf(dv[0], 0.f), fmaxf(dv[1], 0.f));
        qv1 = pkrtz(fmaxf(dv[2], 0.f), fmaxf(dv[3], 0.f));
        qh0 = pkrtz(fmaxf(dh[0], 0.f), fmaxf(dh[1], 0.f));
        qh1 = pkrtz(fmaxf(dh[2], 0.f), fmaxf(dh[3], 0.f));
    };

    // exchange: build GEMM2' B-frag for one kt from two tiles' pack words
    auto xch4 = [&](unsigned a0, unsigned a1, unsigned b0, unsigned b1,
                    bool hasT1) -> f16x8 {
        unsigned e0 = (unsigned)__shfl((int)a0, srcA);
        unsigned e1 = (unsigned)__shfl((int)a1, srcA);
        unsigned e2 = (unsigned)__shfl((int)a0, srcB);
        unsigned e3 = (unsigned)__shfl((int)a1, srcB);
        unsigned f0 = 0, f1 = 0, f2 = 0, f3 = 0;
        if (hasT1) {
            f0 = (unsigned)__shfl((int)b0, srcA);
            f1 = (unsigned)__shfl((int)b1, srcA);
            f2 = (unsigned)__shfl((int)b0, srcB);
            f3 = (unsigned)__shfl((int)b1, srcB);
        }
        Frag U;
        U.u[0] = hiTile ? f0 : e0;
        U.u[1] = hiTile ? f1 : e1;
        U.u[2] = hiTile ? f2 : e2;
        U.u[3] = hiTile ? f3 : e3;
        return U.v;
    };

    f32x4 DV[2] = {fz, fz};
    f32x4 DC[4] = {fz, fz, fz, fz};

    #pragma unroll
    for (int kt = 0; kt < 4; ++kt) {
        const bool h1 = (kt < 3);
        const int t0 = 2 * kt;

        // ---- phase 1: GEMM1' tiles t0 (and t0+1), one at a time ------------
        unsigned Av0, Av1, Ah0, Ah1;
        unsigned Bv0 = 0, Bv1 = 0, Bh0 = 0, Bh1 = 0;
        g1t(t0, Av0, Av1, Ah0, Ah1);
        if (h1) g1t(t0 + 1, Bv0, Bv1, Bh0, Bh1);

        // ---- phase 2: exchange (2 streams) ---------------------------------
        f16x8 bv = xch4(Av0, Av1, Bv0, Bv1, h1);
        f16x8 bh = xch4(Ah0, Ah1, Bh0, Bh1, h1);

        // ---- phase 3: GEMM2' in small register windows ---------------------
        {
            f16x8 w0 = *(const f16x8*)(ws + OFF_W2 + (0 * 4 + kt) * 512 + lane * 8);
            f16x8 w1 = *(const f16x8*)(ws + OFF_W2 + (1 * 4 + kt) * 512 + lane * 8);
            DV[0] = __builtin_amdgcn_mfma_f32_16x16x32_f16(w0, bv, DV[0], 0, 0, 0);
            DV[1] = __builtin_amdgcn_mfma_f32_16x16x32_f16(w1, bv, DV[1], 0, 0, 0);
        }
        #pragma unroll
        for (int t = 0; t < 4; ++t) {
            f16x8 wh = *(const f16x8*)(ws + OFF_W3 + (t * 4 + kt) * 512 + lane * 8);
            DC[t] = __builtin_amdgcn_mfma_f32_16x16x32_f16(wh, bh, DC[t], 0, 0, 0);
        }
    }

    // ---- epilogue: per-lane 8 centroids of its own sample -------------------
    {
        float2 av = ((const float2*)a)[wgbase + m0 + m];
        float num = 0.f, den = 0.f;
        #pragma unroll
        for (int t = 0; t < 4; ++t) {
            #pragma unroll
            for (int p = 0; p < 2; ++p) {
                float x = 5.f * tanh_fast(DC[t][2 * p]);
                float y = 5.f * tanh_fast(DC[t][2 * p + 1]);
                float ex = x - av.x, ey = y - av.y;
                float dist = __builtin_amdgcn_sqrtf(fmaf(ex, ex, ey * ey));
                float wt = exp2f(-4.328085122666891f * dist);   // exp(-3 d)
                if (t == 3 && G == 3) wt = 0.f;      // n = 30,31 pad
                float v = (t < 2) ? DV[0][2 * t + p] : DV[1][2 * (t - 2) + p];
                num = fmaf(wt, v, num);
                den += wt;
            }
        }
        num += __shfl_xor(num, 16); den += __shfl_xor(den, 16);
        num += __shfl_xor(num, 32); den += __shfl_xor(den, 32);
        if (lane < 16) out[wgbase + m0 + m] = num * __builtin_amdgcn_rcpf(den);
    }
}

extern "C" void kernel_launch(void* const* d_in, const int* in_sizes, int n_in,
                              void* d_out, int out_size, void* d_ws, size_t ws_size,
                              hipStream_t stream) {
    const float* s   = (const float*)d_in[0];
    const float* a   = (const float*)d_in[1];
    const float* W1  = (const float*)d_in[2];
    const float* b1  = (const float*)d_in[3];
    const float* W2  = (const float*)d_in[4];
    const float* b2  = (const float*)d_in[5];
    const float* L1  = (const float*)d_in[6];
    const float* bl1 = (const float*)d_in[7];
    const float* WL2 = (const float*)d_in[8];
    const float* bL2 = (const float*)d_in[9];
    float* out = (float*)d_out;
    unsigned short* ws = (unsigned short*)d_ws;

    prep_kernel<<<(TOT_HALVES + 255) / 256, 256, 0, stream>>>(
        W1, b1, W2, b2, L1, bl1, WL2, bL2, ws);

    int Btot = out_size;                 // 524288
    int grid = Btot / 64;                // 8192 WGs, 16 samples/wave
    fused_kernel<<<grid, 256, 0, stream>>>(s, a, ws, out);
}

// Round 15
// 42.015 us; speedup vs baseline: 2.8767x; 1.3672x over previous
//
#include <hip/hip_runtime.h>
#include <hip/hip_fp16.h>

// ---------------------------------------------------------------------------
// Round 15: 32x32x16 restructure. 32 samples/wave, LDS-free, f16 1-term.
//   GEMM1'': D[c][m] = (W|b)^T s^T, 4 tiles x 2 streams, 32x32x16 (K=16>=11)
//   exchange: relu+pkrtz -> q0..q7; B-frag = 2x v_permlane32_swap per stream
//             (w0,w2)=swap(q_{4h},q_{4h+2}), (w1,w3)=swap(q_{4h+1},q_{4h+3})
//   GEMM2'': D[n][m], 3 A-tiles (1 value + 2 centroid) x 7 kt, 32x32x16
//   prep row permutations align value reg (q+8T) with centroid pair q:
//     value row v -> n = (v&0x19)|((v&4)>>1)|((v&2)<<1)
//     centroid tile T row -> (n = 16T + row>>1, d = row&1)
//   epilogue: per-lane 16 centroids of own sample; reduce = 1 shfl_xor(32).
// ---------------------------------------------------------------------------

typedef _Float16 f16x8 __attribute__((ext_vector_type(8)));
typedef __fp16 fp16x2 __attribute__((ext_vector_type(2)));
typedef float f32x16 __attribute__((ext_vector_type(16)));
typedef unsigned u32x2 __attribute__((ext_vector_type(2)));

// half-index offsets inside ws
#define OFF_G1 0        // [stream 0..1][tile 0..3][lane 0..63][j 0..7]
#define OFF_WV 4096     // [kt 0..6][lane][j]
#define OFF_WC 7680     // [T 0..1][kt 0..6][lane][j]
#define TOT_HALVES 14848

__device__ __forceinline__ unsigned pkrtz(float a, float b) {
    union { fp16x2 v; unsigned u; } U;
    U.v = __builtin_amdgcn_cvt_pkrtz(a, b);
    return U.u;
}
__device__ __forceinline__ unsigned pk_rne(float a, float b) {
    union { __half h[2]; unsigned u; } U;
    U.h[0] = __float2half(a);
    U.h[1] = __float2half(b);
    return U.u;
}
__device__ __forceinline__ float tanh_fast(float x) {
    float e = exp2f(2.8853900817779268f * x);
    return 1.f - 2.f * __builtin_amdgcn_rcpf(e + 1.f);
}

// ---------------- prologue: build fragment-layout weights in ws (f16) ------
__global__ __launch_bounds__(256) void prep_kernel(
    const float* __restrict__ W1, const float* __restrict__ b1,
    const float* __restrict__ W2, const float* __restrict__ b2,
    const float* __restrict__ L1, const float* __restrict__ bl1,
    const float* __restrict__ WL2, const float* __restrict__ bL2,
    unsigned short* __restrict__ ws)
{
    int idx = blockIdx.x * 256 + threadIdx.x;
    if (idx >= TOT_HALVES) return;
    float val = 0.f;

    if (idx < OFF_WV) {
        // GEMM1'' A: [r][t][ln][j]; row c = 32t + (ln&31), k = (ln>>5)*8+j
        int r = idx >> 11, t = (idx >> 9) & 3;
        int ln = (idx >> 3) & 63, j = idx & 7;
        int c = 32 * t + (ln & 31);
        int k = (ln >> 5) * 8 + j;
        const float* W  = (r == 0) ? W1 : L1;
        const float* bb = (r == 0) ? b1 : bl1;
        if (c < 100)       val = (k < 10) ? W[k * 100 + c] : ((k == 10) ? bb[c] : 0.f);
        else if (c == 100) val = (k == 10) ? 1.f : 0.f;    // h[100]=1 bias unit
    } else if (idx < OFF_WC) {
        // GEMM2'' value A: row v -> n = bitswap12(v); k = kt*16 + (ln>>5)*8+j
        int i = idx - OFF_WV;
        int kt = i >> 9, ln = (i >> 3) & 63, j = i & 7;
        int v = ln & 31;
        int n = (v & 0x19) | ((v & 4) >> 1) | ((v & 2) << 1);
        int k = kt * 16 + (ln >> 5) * 8 + j;
        if (n < 30) val = (k < 100) ? W2[k * 30 + n] : ((k == 100) ? b2[n] : 0.f);
    } else {
        // GEMM2'' centroid A: [T][kt][ln][j]; row -> (n = 16T + row>>1, d = row&1)
        int i = idx - OFF_WC;
        int T = i / 3584, rem = i % 3584;
        int kt = rem >> 9, ln = (rem >> 3) & 63, j = rem & 7;
        int row = ln & 31;
        int n = 16 * T + (row >> 1), d = row & 1;
        int k = kt * 16 + (ln >> 5) * 8 + j;
        if (n < 30) val = (k < 100) ? WL2[(n * 100 + k) * 2 + d]
                                    : ((k == 100) ? bL2[n * 2 + d] : 0.f);
    }
    union { __half h; unsigned short u; } cv;
    cv.h = __float2half(val);            // RNE
    ws[idx] = cv.u;
}

// ---------------- main fused kernel (no LDS, 32 samples/wave) --------------
__global__ __launch_bounds__(256, 2) void fused_kernel(
    const float* __restrict__ s, const float* __restrict__ a,
    const unsigned short* __restrict__ ws, float* __restrict__ out)
{
    const int tid  = threadIdx.x;
    const int lane = tid & 63;
    const int wave = tid >> 6;
    const int m32  = lane & 31;
    const int hi   = lane >> 5;
    const int sample = blockIdx.x * 128 + wave * 32 + m32;

    union Frag { f16x8 v; unsigned u[4]; };
    const f32x16 z16 = {0,0,0,0, 0,0,0,0, 0,0,0,0, 0,0,0,0};

    // ---- s^T B-frag: col = m32, k = hi*8 + j; k=10 bias-1 (hi=1, j=2) ------
    f16x8 sf;
    {
        Frag H;
        H.u[0] = 0; H.u[1] = 0; H.u[2] = 0; H.u[3] = 0;
        const float2* p = (const float2*)(s + (size_t)sample * 10);
        if (hi == 0) {
            float2 q0 = p[0], q1 = p[1], q2 = p[2], q3 = p[3];
            H.u[0] = pk_rne(q0.x, q0.y);
            H.u[1] = pk_rne(q1.x, q1.y);
            H.u[2] = pk_rne(q2.x, q2.y);
            H.u[3] = pk_rne(q3.x, q3.y);
        } else {
            float2 q4 = p[4];
            H.u[0] = pk_rne(q4.x, q4.y);     // k = 8, 9
            H.u[1] = 0x00003C00u;            // k = 10 -> f16 1.0 (bias row)
        }
        sf = H.v;
    }

    f32x16 DV = z16, DC0 = z16, DC1 = z16;

    #pragma unroll
    for (int t = 0; t < 4; ++t) {
        // ---- GEMM1'' tile t, both streams ----------------------------------
        f16x8 aV = *(const f16x8*)(ws + OFF_G1 + (0 * 4 + t) * 512 + lane * 8);
        f16x8 aH = *(const f16x8*)(ws + OFF_G1 + (1 * 4 + t) * 512 + lane * 8);
        f32x16 dv = __builtin_amdgcn_mfma_f32_32x32x16_f16(aV, sf, z16, 0, 0, 0);
        f32x16 dh = __builtin_amdgcn_mfma_f32_32x32x16_f16(aH, sf, z16, 0, 0, 0);

        unsigned qv[8], qh[8];
        #pragma unroll
        for (int q = 0; q < 8; ++q) {
            qv[q] = pkrtz(fmaxf(dv[2 * q], 0.f), fmaxf(dv[2 * q + 1], 0.f));
            qh[q] = pkrtz(fmaxf(dh[2 * q], 0.f), fmaxf(dh[2 * q + 1], 0.f));
        }

        // ---- consume kt = 2t (+1): exchange via permlane32_swap + GEMM2'' --
        #pragma unroll
        for (int half = 0; half < 2; ++half) {
            const int kt = 2 * t + half;
            if (kt < 7) {
                u32x2 sv0 = __builtin_amdgcn_permlane32_swap(qv[4*half+0], qv[4*half+2], false, false);
                u32x2 sv1 = __builtin_amdgcn_permlane32_swap(qv[4*half+1], qv[4*half+3], false, false);
                u32x2 sh0 = __builtin_amdgcn_permlane32_swap(qh[4*half+0], qh[4*half+2], false, false);
                u32x2 sh1 = __builtin_amdgcn_permlane32_swap(qh[4*half+1], qh[4*half+3], false, false);
                Frag BV, BH;
                BV.u[0] = sv0.x; BV.u[1] = sv1.x; BV.u[2] = sv0.y; BV.u[3] = sv1.y;
                BH.u[0] = sh0.x; BH.u[1] = sh1.x; BH.u[2] = sh0.y; BH.u[3] = sh1.y;

                f16x8 wv  = *(const f16x8*)(ws + OFF_WV + kt * 512 + lane * 8);
                f16x8 wc0 = *(const f16x8*)(ws + OFF_WC + (0 * 7 + kt) * 512 + lane * 8);
                f16x8 wc1 = *(const f16x8*)(ws + OFF_WC + (1 * 7 + kt) * 512 + lane * 8);
                DV  = __builtin_amdgcn_mfma_f32_32x32x16_f16(wv,  BV.v, DV,  0, 0, 0);
                DC0 = __builtin_amdgcn_mfma_f32_32x32x16_f16(wc0, BH.v, DC0, 0, 0, 0);
                DC1 = __builtin_amdgcn_mfma_f32_32x32x16_f16(wc1, BH.v, DC1, 0, 0, 0);
            }
        }
    }

    // ---- epilogue: 16 centroids/lane; value reg = q + 8T -------------------
    {
        float2 av = ((const float2*)a)[sample];
        float num = 0.f, den = 0.f;
        #pragma unroll
        for (int T = 0; T < 2; ++T) {
            #pragma unroll
            for (int q = 0; q < 8; ++q) {
                float cx = (T == 0) ? DC0[2 * q]     : DC1[2 * q];
                float cy = (T == 0) ? DC0[2 * q + 1] : DC1[2 * q + 1];
                float x = 5.f * tanh_fast(cx);
                float y = 5.f * tanh_fast(cy);
                float ex = x - av.x, ey = y - av.y;
                float dist = __builtin_amdgcn_sqrtf(fmaf(ex, ex, ey * ey));
                float wt = exp2f(-4.328085122666891f * dist);   // exp(-3 d)
                if (T == 1 && hi == 1 && q >= 6) wt = 0.f;      // n = 30, 31 pad
                num = fmaf(wt, DV[q + 8 * T], num);
                den += wt;
            }
        }
        num += __shfl_xor(num, 32);
        den += __shfl_xor(den, 32);
        if (lane < 32) out[sample] = num * __builtin_amdgcn_rcpf(den);
    }
}

extern "C" void kernel_launch(void* const* d_in, const int* in_sizes, int n_in,
                              void* d_out, int out_size, void* d_ws, size_t ws_size,
                              hipStream_t stream) {
    const float* s   = (const float*)d_in[0];
    const float* a   = (const float*)d_in[1];
    const float* W1  = (const float*)d_in[2];
    const float* b1  = (const float*)d_in[3];
    const float* W2  = (const float*)d_in[4];
    const float* b2  = (const float*)d_in[5];
    const float* L1  = (const float*)d_in[6];
    const float* bl1 = (const float*)d_in[7];
    const float* WL2 = (const float*)d_in[8];
    const float* bL2 = (const float*)d_in[9];
    float* out = (float*)d_out;
    unsigned short* ws = (unsigned short*)d_ws;

    prep_kernel<<<(TOT_HALVES + 255) / 256, 256, 0, stream>>>(
        W1, b1, W2, b2, L1, bl1, WL2, bL2, ws);

    int Btot = out_size;                 // 524288
    int grid = Btot / 128;               // 4096 WGs, 32 samples/wave
    fused_kernel<<<grid, 256, 0, stream>>>(s, a, ws, out);
}